// Round 9
// baseline (96.426 us; speedup 1.0000x reference)
//
#include <hip/hip_runtime.h>
#include <stdint.h>

#define NBINS 100
#define FF 16
#define CC 16
#define GRID 256
#define MM_THREADS 1024
#define K2_THREADS 1024
#define SPR 64            // samples per round in main phase (K2_THREADS/16)

// ---------- workspace layout (bytes) ----------
// [0     ) unsigned partials[256*32] : 32768 B (per-block min/max, order-encoded)
// [32768 ) unsigned counts[16*100]   : 6400 B
// [39168 ) unsigned bar[1]           : 4 B    (grid-barrier arrival counter)

__device__ __forceinline__ unsigned enc_f(float v) {
    unsigned u = __float_as_uint(v);
    return (u & 0x80000000u) ? ~u : (u | 0x80000000u);
}
__device__ __forceinline__ float dec_f(unsigned e) {
    unsigned u = (e & 0x80000000u) ? (e ^ 0x80000000u) : ~e;
    return __uint_as_float(u);
}
__device__ __forceinline__ unsigned shfl_xor_u(unsigned x, int m) {
    return (unsigned)__shfl_xor((int)x, m, 64);
}
// exact JAX linspace edge: lo + (hi-lo)*t_k, t_k = k*0.01f (f32), t_100 = 1.0f.
// Deterministic IEEE ops -> bit-identical everywhere it is evaluated.
__device__ __forceinline__ float edgeval(float lo, float d, int k) {
    float tt = (k == NBINS) ? 1.0f : __fmul_rn((float)k, 0.01f);
    return __fadd_rn(lo, __fmul_rn(d, tt));
}
// Branchless searchsorted-1. Guess error <=2 index units for this data
// (normal(0,1) inputs: rounding terms <=2e-5 index units); window [a+1, a+5]
// with a = clamp(ig-3, -1, 95) covers truth. Result in [-1, 100].
__device__ __forceinline__ int search_left(float v, float lo, float dd, float scl) {
    int ig = (int)((v - lo) * scl);
    int a = ig - 3;
    a = a < -1 ? -1 : (a > 95 ? 95 : a);
    int g = a;
#pragma unroll
    for (int j = 1; j <= 5; ++j) g += (edgeval(lo, dd, a + j) < v) ? 1 : 0;
    return g;
}
__device__ __forceinline__ int search_right(float v, float lo, float dd, float scl) {
    int ig = (int)((v - lo) * scl);
    int a = ig - 3;
    a = a < -1 ? -1 : (a > 95 ? 95 : a);
    int g = a;
#pragma unroll
    for (int j = 1; j <= 5; ++j) g += (edgeval(lo, dd, a + j) <= v) ? 1 : 0;
    return g;
}
// Q/P lookup exact for g in [-1,100]: Q=cum[clamp(g,0,99)], P=(g<1?0:cum[min(g-1,99)])
__device__ __forceinline__ float qlook(const float* cumf, int g) {
    int i = g < 0 ? 0 : (g > NBINS - 1 ? NBINS - 1 : g);
    return cumf[i];
}
__device__ __forceinline__ float plook(const float* cumf, int g) {
    int i = g - 1;
    i = i > NBINS - 1 ? NBINS - 1 : i;
    return (g >= 1) ? cumf[i] : 0.0f;
}

// K1: per-block min/max partials over combined=[z;cl] (float4); zero counts+bar.
__global__ __launch_bounds__(1024) void k_minmax(const float4* __restrict__ z4,
                                                 const float4* __restrict__ cl4,
                                                 int zn4, int total4,
                                                 unsigned* __restrict__ partials,
                                                 unsigned* __restrict__ counts,
                                                 unsigned* __restrict__ bar) {
    int t = threadIdx.x;
    int gtid = blockIdx.x * MM_THREADS + t;
    if (gtid < FF * NBINS) counts[gtid] = 0u;   // zero for K2's atomics
    if (gtid == FF * NBINS) *bar = 0u;          // zero grid-barrier counter

    unsigned mn[4] = {~0u, ~0u, ~0u, ~0u}, mx[4] = {0u, 0u, 0u, 0u};
    int stride = GRID * MM_THREADS;             // float4 units; 4*stride % 16 == 0
    for (int i = gtid; i < total4; i += stride) {
        float4 v = (i < zn4) ? z4[i] : cl4[i - zn4];
        unsigned e;
        e = enc_f(v.x); mn[0] = min(mn[0], e); mx[0] = max(mx[0], e);
        e = enc_f(v.y); mn[1] = min(mn[1], e); mx[1] = max(mx[1], e);
        e = enc_f(v.z); mn[2] = min(mn[2], e); mx[2] = max(mx[2], e);
        e = enc_f(v.w); mn[3] = min(mn[3], e); mx[3] = max(mx[3], e);
    }
    // lane l, component c covers feature (4l+c)&15; lanes l and l^4 share features
#pragma unroll
    for (int off = 4; off < 64; off <<= 1) {
#pragma unroll
        for (int c = 0; c < 4; ++c) {
            mn[c] = min(mn[c], shfl_xor_u(mn[c], off));
            mx[c] = max(mx[c], shfl_xor_u(mx[c], off));
        }
    }
    __shared__ unsigned smin[16][16], smax[16][16];
    int wave = t >> 6, lane = t & 63;
    if (lane < 4) {
#pragma unroll
        for (int c = 0; c < 4; ++c) {
            smin[wave][4 * lane + c] = mn[c];
            smax[wave][4 * lane + c] = mx[c];
        }
    }
    __syncthreads();
    if (t < 16) {
        unsigned um = ~0u, ux = 0u;
#pragma unroll
        for (int w = 0; w < 16; ++w) {
            um = min(um, smin[w][t]);
            ux = max(ux, smax[w][t]);
        }
        partials[blockIdx.x * 32 + t] = um;
        partials[blockIdx.x * 32 + 16 + t] = ux;
    }
}

// K2: edges from partials; branchless histogram -> global counts; device-scope
// grid barrier (R6-proven); cumsum + cluster QP; per-(sample,cluster) output.
// scnt(s,cb) = max(Qs,Qc) - min(Ps,Pc)  (exact identity, Q/P monotone in bin)
__global__ __launch_bounds__(1024) void k_rest(
        const float4* __restrict__ z4, const float4* __restrict__ cl4,
        int zn4, int total4, int N, float inv_div,
        const unsigned* __restrict__ partials, unsigned* __restrict__ counts,
        unsigned* __restrict__ bar, const float* __restrict__ cl,
        const float* __restrict__ z, float* __restrict__ out)
{
    __shared__ unsigned ulo[16], uhi[16];
    __shared__ float slo[16], sd[16], sscl[16];
    __shared__ unsigned sc[FF * NBINS];
    __shared__ float scum[FF * NBINS];
    __shared__ float2 sqs[SPR * 17];              // [nl][f], row stride 17 (pad)
    __shared__ float2 sqp[FF * CC];               // [f][c]
    int t = threadIdx.x;
    int gtid = blockIdx.x * K2_THREADS + t;
    int gsz = GRID * K2_THREADS;

    for (int i = t; i < FF * NBINS; i += K2_THREADS) sc[i] = 0u;
    if (t < 16) { ulo[t] = ~0u; uhi[t] = 0u; }
    __syncthreads();
    {   // reduce 256-block partials: 64 chunks of 4 blocks per feature
        int f = t & 15, b0 = (t >> 4) * (GRID / 64);
        unsigned um = ~0u, ux = 0u;
#pragma unroll
        for (int b = b0; b < b0 + GRID / 64; ++b) {
            um = min(um, partials[b * 32 + f]);
            ux = max(ux, partials[b * 32 + 16 + f]);
        }
        atomicMin(&ulo[f], um);
        atomicMax(&uhi[f], ux);
    }
    __syncthreads();
    if (t < 16) {
        float lo = dec_f(ulo[t]), hi = dec_f(uhi[t]);
        float d = __fsub_rn(hi, lo);
        slo[t] = lo; sd[t] = d;
        sscl[t] = d > 0.0f ? 100.0f / d : 0.0f;   // guess only; window is exact
    }
    __syncthreads();

    // ---- histogram phase: branchless search_right, LDS atomics ----
    int fb = (4 * gtid) & 15;                     // feature of component 0 (fixed)
    float lo_c[4], d_c[4], scl_c[4];
#pragma unroll
    for (int c = 0; c < 4; ++c) {
        int f = (fb + c) & 15;
        lo_c[c] = slo[f]; d_c[c] = sd[f]; scl_c[c] = sscl[f];
    }
    for (int i = gtid; i < total4; i += gsz) {
        float4 v4 = (i < zn4) ? z4[i] : cl4[i - zn4];
        float vv[4] = {v4.x, v4.y, v4.z, v4.w};
#pragma unroll
        for (int c = 0; c < 4; ++c) {
            int f = (fb + c) & 15;
            int g = search_right(vv[c], lo_c[c], d_c[c], scl_c[c]);
            g = g < 0 ? 0 : (g > NBINS - 1 ? NBINS - 1 : g);   // torch clip
            atomicAdd(&sc[f * NBINS + g], 1u);
        }
    }
    __syncthreads();
    for (int i = t; i < FF * NBINS; i += K2_THREADS) {
        unsigned c = sc[i];
        if (c) atomicAdd(&counts[i], c);          // device(agent)-scope atomics
    }
    __syncthreads();

    // ---- manual grid barrier (counter zeroed by K1; R6-proven pattern) ----
    if (t == 0) {
        __hip_atomic_fetch_add(bar, 1u, __ATOMIC_RELEASE, __HIP_MEMORY_SCOPE_AGENT);
        while (__hip_atomic_load(bar, __ATOMIC_ACQUIRE, __HIP_MEMORY_SCOPE_AGENT)
               < (unsigned)GRID) {
            __builtin_amdgcn_s_sleep(2);
        }
    }
    __syncthreads();

    // ---- cumsum (agent-scope coherent reads) + cluster QP ----
    for (int i = t; i < FF * NBINS; i += K2_THREADS)
        sc[i] = __hip_atomic_load(&counts[i], __ATOMIC_RELAXED,
                                  __HIP_MEMORY_SCOPE_AGENT);
    __syncthreads();
    if (t < 16) {                                 // serial cumsum, exact (< 2^24)
        float s = 0.0f;
        const unsigned* cp = &sc[t * NBINS];
        float* fp = &scum[t * NBINS];
#pragma unroll
        for (int k = 0; k < NBINS; ++k) { s += (float)cp[k]; fp[k] = s; }
    }
    __syncthreads();
    if (t < CC * FF) {                            // cluster QP: c=t&15, f=t>>4
        int c = t & 15, f = t >> 4;
        float v = cl[c * FF + f];
        int g = search_left(v, slo[f], sd[f], sscl[f]);
        const float* cumf = &scum[f * NBINS];
        sqp[f * CC + c] = make_float2(qlook(cumf, g), plook(cumf, g));
    }
    __syncthreads();

    // ---- main phase: rounds of SPR samples x 16 clusters = 1024 threads ----
    int nrounds = (N + SPR - 1) / SPR;
    for (int r = blockIdx.x; r < nrounds; r += GRID) {
        int n0 = r * SPR;
        {   // searches: nl = t>>4 in [0,64), f = t&15 (coalesced z reads)
            int nl = t >> 4, f = t & 15;
            int n = n0 + nl;
            if (n < N) {
                float v = z[(size_t)n * FF + f];
                int g = search_left(v, slo[f], sd[f], sscl[f]);
                const float* cumf = &scum[f * NBINS];
                sqs[nl * 17 + f] = make_float2(qlook(cumf, g), plook(cumf, g));
            }
        }
        __syncthreads();
        {   // compute: nl = t>>4, c = t&15
            int nl = t >> 4, c = t & 15;
            int n = n0 + nl;
            if (n < N) {
                float acc = 0.0f;
#pragma unroll
                for (int f = 0; f < FF; ++f) {
                    float2 s = sqs[nl * 17 + f];  // broadcast within 16-lane group
                    float2 p = sqp[f * CC + c];   // 16 even banks: conflict-free
                    float h = fmaxf(s.x, p.x);
                    float l = fminf(s.y, p.y);
                    float d = h - l;
                    acc = fmaf(d, d, acc);
                }
                float mass = sqrtf(acc) * inv_div;
                float qq = 1.0f / (1.0f + mass);
                float rs = qq;
                rs += __shfl_xor(rs, 1, 64);
                rs += __shfl_xor(rs, 2, 64);
                rs += __shfl_xor(rs, 4, 64);
                rs += __shfl_xor(rs, 8, 64);
                out[(size_t)n * CC + c] = qq / rs;  // 256B/wave, coalesced
            }
        }
        __syncthreads();                          // protect sqs for next round
    }
}

extern "C" void kernel_launch(void* const* d_in, const int* in_sizes, int n_in,
                              void* d_out, int out_size, void* d_ws, size_t ws_size,
                              hipStream_t stream) {
    const float* z  = (const float*)d_in[0];
    const float* cl = (const float*)d_in[1];
    float* out = (float*)d_out;
    int N = in_sizes[0] / FF;

    char* ws = (char*)d_ws;
    unsigned* partials = (unsigned*)(ws);
    unsigned* counts   = (unsigned*)(ws + 32768);
    unsigned* bar      = (unsigned*)(ws + 39168);

    const float4* z4  = (const float4*)d_in[0];
    const float4* cl4 = (const float4*)d_in[1];
    int zn4 = N * FF / 4;
    int total4 = (N + CC) * FF / 4;
    float inv_div = 1.0f / (float)(N + CC);

    k_minmax<<<GRID, MM_THREADS, 0, stream>>>(z4, cl4, zn4, total4,
                                              partials, counts, bar);
    k_rest<<<GRID, K2_THREADS, 0, stream>>>(z4, cl4, zn4, total4, N, inv_div,
                                            partials, counts, bar, cl, z, out);
}

// Round 10
// 86.116 us; speedup vs baseline: 1.1197x; 1.1197x over previous
//
#include <hip/hip_runtime.h>
#include <stdint.h>

#define NBINS 100
#define FF 16
#define CC 16
#define MM_BLOCKS 256
#define MM_THREADS 1024
#define H_BLOCKS 256
#define H_THREADS 1024
#define M_THREADS 256

// ---------- workspace layout (bytes) ----------
// [0     ) unsigned partials[256*32] : 32768 B (per-block min/max, order-encoded)
// [32768 ) unsigned counts[16*100]   : 6400 B
// [39168 ) float    params[48]       : 192 B  (lo[16], d[16], scl[16])

__device__ __forceinline__ unsigned enc_f(float v) {
    unsigned u = __float_as_uint(v);
    return (u & 0x80000000u) ? ~u : (u | 0x80000000u);
}
__device__ __forceinline__ float dec_f(unsigned e) {
    unsigned u = (e & 0x80000000u) ? (e ^ 0x80000000u) : ~e;
    return __uint_as_float(u);
}
__device__ __forceinline__ unsigned shfl_xor_u(unsigned x, int m) {
    return (unsigned)__shfl_xor((int)x, m, 64);
}
// exact JAX linspace edge: lo + (hi-lo)*t_k, t_k = k*0.01f (f32), t_100 = 1.0f.
// Deterministic IEEE ops -> bit-identical everywhere it is evaluated.
__device__ __forceinline__ float edgeval(float lo, float d, int k) {
    float tt = (k == NBINS) ? 1.0f : __fmul_rn((float)k, 0.01f);
    return __fadd_rn(lo, __fmul_rn(d, tt));
}
// Branchless searchsorted-1 (R8-verified). Guess error <=2 index units for
// this data; window [a+1, a+5], a = clamp(ig-3, -1, 95). Result in [-1, 100].
__device__ __forceinline__ int search_left(float v, float lo, float dd, float scl) {
    int ig = (int)((v - lo) * scl);
    int a = ig - 3;
    a = a < -1 ? -1 : (a > 95 ? 95 : a);
    int g = a;
#pragma unroll
    for (int j = 1; j <= 5; ++j) g += (edgeval(lo, dd, a + j) < v) ? 1 : 0;
    return g;
}
__device__ __forceinline__ int search_right(float v, float lo, float dd, float scl) {
    int ig = (int)((v - lo) * scl);
    int a = ig - 3;
    a = a < -1 ? -1 : (a > 95 ? 95 : a);
    int g = a;
#pragma unroll
    for (int j = 1; j <= 5; ++j) g += (edgeval(lo, dd, a + j) <= v) ? 1 : 0;
    return g;
}
// Q/P lookup exact for g in [-1,100]: Q=cum[clamp(g,0,99)], P=(g<1?0:cum[min(g-1,99)])
__device__ __forceinline__ float qlook(const float* cumf, int g) {
    int i = g < 0 ? 0 : (g > NBINS - 1 ? NBINS - 1 : g);
    return cumf[i];
}
__device__ __forceinline__ float plook(const float* cumf, int g) {
    int i = g - 1;
    i = i > NBINS - 1 ? NBINS - 1 : i;
    return (g >= 1) ? cumf[i] : 0.0f;
}

// K1: per-block min/max partials over combined=[z;cl] (float4); zero counts.
__global__ __launch_bounds__(1024) void k_minmax(const float4* __restrict__ z4,
                                                 const float4* __restrict__ cl4,
                                                 int zn4, int total4,
                                                 unsigned* __restrict__ partials,
                                                 unsigned* __restrict__ counts) {
    int t = threadIdx.x;
    int gtid = blockIdx.x * MM_THREADS + t;
    if (gtid < FF * NBINS) counts[gtid] = 0u;   // zero for K2's atomics

    unsigned mn[4] = {~0u, ~0u, ~0u, ~0u}, mx[4] = {0u, 0u, 0u, 0u};
    int stride = MM_BLOCKS * MM_THREADS;        // float4 units; 4*stride % 16 == 0
    for (int i = gtid; i < total4; i += stride) {
        float4 v = (i < zn4) ? z4[i] : cl4[i - zn4];
        unsigned e;
        e = enc_f(v.x); mn[0] = min(mn[0], e); mx[0] = max(mx[0], e);
        e = enc_f(v.y); mn[1] = min(mn[1], e); mx[1] = max(mx[1], e);
        e = enc_f(v.z); mn[2] = min(mn[2], e); mx[2] = max(mx[2], e);
        e = enc_f(v.w); mn[3] = min(mn[3], e); mx[3] = max(mx[3], e);
    }
#pragma unroll
    for (int off = 4; off < 64; off <<= 1) {
#pragma unroll
        for (int c = 0; c < 4; ++c) {
            mn[c] = min(mn[c], shfl_xor_u(mn[c], off));
            mx[c] = max(mx[c], shfl_xor_u(mx[c], off));
        }
    }
    __shared__ unsigned smin[16][16], smax[16][16];
    int wave = t >> 6, lane = t & 63;
    if (lane < 4) {
#pragma unroll
        for (int c = 0; c < 4; ++c) {
            smin[wave][4 * lane + c] = mn[c];
            smax[wave][4 * lane + c] = mx[c];
        }
    }
    __syncthreads();
    if (t < 16) {
        unsigned um = ~0u, ux = 0u;
#pragma unroll
        for (int w = 0; w < 16; ++w) {
            um = min(um, smin[w][t]);
            ux = max(ux, smax[w][t]);
        }
        partials[blockIdx.x * 32 + t] = um;
        partials[blockIdx.x * 32 + 16 + t] = ux;
    }
}

// K2: edges from partials; branchless histogram; block 0 publishes params.
__global__ __launch_bounds__(1024) void k_hist(const float4* __restrict__ z4,
                                               const float4* __restrict__ cl4,
                                               int zn4, int total4,
                                               const unsigned* __restrict__ partials,
                                               unsigned* __restrict__ counts,
                                               float* __restrict__ params) {
    __shared__ unsigned ulo[16], uhi[16];
    __shared__ float slo[16], sd[16], sscl[16];
    __shared__ unsigned sc[FF * NBINS];
    int t = threadIdx.x;
    for (int i = t; i < FF * NBINS; i += H_THREADS) sc[i] = 0u;
    if (t < 16) { ulo[t] = ~0u; uhi[t] = 0u; }
    __syncthreads();
    {   // reduce 256-block partials: 64 chunks of 4 blocks per feature
        int f = t & 15, b0 = (t >> 4) * (MM_BLOCKS / 64);
        unsigned um = ~0u, ux = 0u;
#pragma unroll
        for (int b = b0; b < b0 + MM_BLOCKS / 64; ++b) {
            um = min(um, partials[b * 32 + f]);
            ux = max(ux, partials[b * 32 + 16 + f]);
        }
        atomicMin(&ulo[f], um);
        atomicMax(&uhi[f], ux);
    }
    __syncthreads();
    if (t < 16) {
        float lo = dec_f(ulo[t]), hi = dec_f(uhi[t]);
        float d = __fsub_rn(hi, lo);
        slo[t] = lo; sd[t] = d;
        sscl[t] = d > 0.0f ? 100.0f / d : 0.0f;   // guess only; window is exact
        if (blockIdx.x == 0) {
            params[t] = lo; params[16 + t] = d; params[32 + t] = sscl[t];
        }
    }
    __syncthreads();

    int gtid = blockIdx.x * H_THREADS + t;
    int stride = H_BLOCKS * H_THREADS;            // 4*stride % 16 == 0
    int fb = (4 * gtid) & 15;                     // feature of component 0 (fixed)
    float lo_c[4], d_c[4], scl_c[4];
#pragma unroll
    for (int c = 0; c < 4; ++c) {
        int f = (fb + c) & 15;
        lo_c[c] = slo[f]; d_c[c] = sd[f]; scl_c[c] = sscl[f];
    }
    for (int i = gtid; i < total4; i += stride) {
        float4 v4 = (i < zn4) ? z4[i] : cl4[i - zn4];
        float vv[4] = {v4.x, v4.y, v4.z, v4.w};
#pragma unroll
        for (int c = 0; c < 4; ++c) {
            int f = (fb + c) & 15;
            int g = search_right(vv[c], lo_c[c], d_c[c], scl_c[c]);
            g = g < 0 ? 0 : (g > NBINS - 1 ? NBINS - 1 : g);   // torch clip
            atomicAdd(&sc[f * NBINS + g], 1u);
        }
    }
    __syncthreads();
    for (int i = t; i < FF * NBINS; i += H_THREADS) {
        unsigned c = sc[i];
        if (c) atomicAdd(&counts[i], c);
    }
}

// K3: one thread per sample. Parallel scan preamble; Qs/Ps in registers;
// inner loop reads only wave-uniform float4 sqp (2 (c,f) pairs per b128).
// scnt(s,cb) = max(Qs,Qc) - min(Ps,Pc)  (exact identity, Q/P monotone in bin)
__global__ __launch_bounds__(256) void k_main(const float4* __restrict__ z4, int N,
                                              float inv_div,
                                              const unsigned* __restrict__ counts,
                                              const float* __restrict__ params,
                                              const float* __restrict__ cl,
                                              float* __restrict__ out) {
    __shared__ float sparam[48];                  // lo[16], d[16], scl[16]
    __shared__ float scnt[FF * NBINS];
    __shared__ float scum[FF * NBINS];
    __shared__ float sqp[CC * 32];                // [c][2f]=Qc, [2f+1]=Pc
    int t = threadIdx.x;
    if (t < 48) sparam[t] = params[t];
    for (int i = t; i < FF * NBINS; i += M_THREADS) scnt[i] = (float)counts[i];
    __syncthreads();
    {   // parallel cumsum: f=t>>4 (one 16-lane group per feature), j=t&15
        // chunk [7j, 7j+7); integer-valued f32 -> exact in any order
        int f = t >> 4, j = t & 15;
        int b0 = j * 7;
        float loc[7];
        float s = 0.0f;
#pragma unroll
        for (int k = 0; k < 7; ++k) {
            int b = b0 + k;
            float v = (b < NBINS) ? scnt[f * NBINS + b] : 0.0f;
            s += v;
            loc[k] = s;                           // inclusive within chunk
        }
        float ss = s;                             // inclusive scan of chunk sums
#pragma unroll
        for (int off = 1; off < 16; off <<= 1) {
            float up = __shfl_up(ss, off, 16);    // 16-lane segments
            if (j >= off) ss += up;
        }
        float pre = ss - s;                       // exclusive prefix (exact ints)
#pragma unroll
        for (int k = 0; k < 7; ++k) {
            int b = b0 + k;
            if (b < NBINS) scum[f * NBINS + b] = pre + loc[k];
        }
    }
    __syncthreads();
    {   // cluster QP: c=t&15, f=t>>4
        int c = t & 15, f = t >> 4;
        float v = cl[c * FF + f];
        int g = search_left(v, sparam[f], sparam[16 + f], sparam[32 + f]);
        const float* cumf = &scum[f * NBINS];
        sqp[c * 32 + 2 * f]     = qlook(cumf, g);
        sqp[c * 32 + 2 * f + 1] = plook(cumf, g);
    }
    __syncthreads();

    int n = blockIdx.x * M_THREADS + t;
    if (n >= N) return;

    float v[FF];
    const float4* zr = z4 + (size_t)n * 4;
    float4 a0 = zr[0], a1 = zr[1], a2 = zr[2], a3 = zr[3];
    v[0] = a0.x; v[1] = a0.y; v[2]  = a0.z; v[3]  = a0.w;
    v[4] = a1.x; v[5] = a1.y; v[6]  = a1.z; v[7]  = a1.w;
    v[8] = a2.x; v[9] = a2.y; v[10] = a2.z; v[11] = a2.w;
    v[12] = a3.x; v[13] = a3.y; v[14] = a3.z; v[15] = a3.w;

    float Qs[FF], Ps[FF];
#pragma unroll
    for (int f = 0; f < FF; ++f) {
        int g = search_left(v[f], sparam[f], sparam[16 + f], sparam[32 + f]);
        const float* cumf = &scum[f * NBINS];
        Qs[f] = qlook(cumf, g);
        Ps[f] = plook(cumf, g);
    }

    float q[CC];
    float rowsum = 0.0f;
#pragma unroll
    for (int c = 0; c < CC; ++c) {
        float acc = 0.0f;
        const float4* qprow = (const float4*)&sqp[c * 32];
#pragma unroll
        for (int f2 = 0; f2 < 8; ++f2) {
            float4 qp = qprow[f2];                // wave-uniform b128: 2 DS/sample
            float h0 = fmaxf(Qs[2 * f2], qp.x);
            float l0 = fminf(Ps[2 * f2], qp.y);
            float d0 = h0 - l0;
            acc = fmaf(d0, d0, acc);
            float h1 = fmaxf(Qs[2 * f2 + 1], qp.z);
            float l1 = fminf(Ps[2 * f2 + 1], qp.w);
            float d1 = h1 - l1;
            acc = fmaf(d1, d1, acc);
        }
        float mass = sqrtf(acc) * inv_div;
        float qq = 1.0f / (1.0f + mass);
        q[c] = qq;
        rowsum += qq;
    }

    float* op = out + (size_t)n * CC;
    float4 o;
    o.x = q[0] / rowsum;  o.y = q[1] / rowsum;  o.z = q[2] / rowsum;  o.w = q[3] / rowsum;
    ((float4*)op)[0] = o;
    o.x = q[4] / rowsum;  o.y = q[5] / rowsum;  o.z = q[6] / rowsum;  o.w = q[7] / rowsum;
    ((float4*)op)[1] = o;
    o.x = q[8] / rowsum;  o.y = q[9] / rowsum;  o.z = q[10] / rowsum; o.w = q[11] / rowsum;
    ((float4*)op)[2] = o;
    o.x = q[12] / rowsum; o.y = q[13] / rowsum; o.z = q[14] / rowsum; o.w = q[15] / rowsum;
    ((float4*)op)[3] = o;
}

extern "C" void kernel_launch(void* const* d_in, const int* in_sizes, int n_in,
                              void* d_out, int out_size, void* d_ws, size_t ws_size,
                              hipStream_t stream) {
    const float* cl = (const float*)d_in[1];
    float* out = (float*)d_out;
    int N = in_sizes[0] / FF;

    char* ws = (char*)d_ws;
    unsigned* partials = (unsigned*)(ws);
    unsigned* counts   = (unsigned*)(ws + 32768);
    float*    params   = (float*)(ws + 39168);

    const float4* z4  = (const float4*)d_in[0];
    const float4* cl4 = (const float4*)d_in[1];
    int zn4 = N * FF / 4;
    int total4 = (N + CC) * FF / 4;
    float inv_div = 1.0f / (float)(N + CC);

    k_minmax<<<MM_BLOCKS, MM_THREADS, 0, stream>>>(z4, cl4, zn4, total4,
                                                   partials, counts);
    k_hist<<<H_BLOCKS, H_THREADS, 0, stream>>>(z4, cl4, zn4, total4,
                                               partials, counts, params);
    int mblocks = (N + M_THREADS - 1) / M_THREADS;
    k_main<<<mblocks, M_THREADS, 0, stream>>>(z4, N, inv_div, counts, params,
                                              cl, out);
}